// Round 5
// baseline (92.903 us; speedup 1.0000x reference)
//
#include <hip/hip_runtime.h>

#define FLOW_EPS 0.1f

// XOR involution applied to BOTH the global-source float4 index (pre-swizzle)
// and the LDS read index (rule #21: both-sides-or-neither with global_load_lds).
// Keeps gload sources a within-128B permutation (fully coalesced) and makes the
// per-thread stride-9/stride-3 float4 LDS reads bank-balanced.
#define SWZ(f) ((f) ^ (((f) >> 4) & 7))

#define WAITVM(n) asm volatile("s_waitcnt vmcnt(" #n ")" ::: "memory")
#define WAITLGKM0() asm volatile("s_waitcnt lgkmcnt(0)" ::: "memory")

#define GLOBAL_AS const __attribute__((address_space(1))) void*
#define LDS_AS __attribute__((address_space(3))) void*

__device__ __forceinline__ void flow_compute(const float* wl, const float* bl,
                                             float& z0, float& z1, float& z2,
                                             float& ld)
{
#pragma unroll
    for (int k = 0; k < 4; ++k) {
        const int o = k * 9;
        const float w00 = wl[o + 0], w01 = wl[o + 1], w02 = wl[o + 2];
        const float w10 = wl[o + 3], w11 = wl[o + 4], w12 = wl[o + 5];
        const float w20 = wl[o + 6], w21 = wl[o + 7], w22 = wl[o + 8];

        const float d0 = fabsf(w00) + FLOW_EPS;
        const float d1 = fabsf(w11) + FLOW_EPS;
        const float d2 = fabsf(w22) + FLOW_EPS;

        // t = z @ L (unit lower-tri), s = t * d, z = s @ U + b (unit upper-tri)
        const float t0 = fmaf(z2, w20, fmaf(z1, w10, z0));
        const float t1 = fmaf(z2, w21, z1);
        const float t2 = z2;
        const float s0 = t0 * d0;
        const float s1 = t1 * d1;
        const float s2 = t2 * d2;
        z0 = s0 + bl[k * 3 + 0];
        z1 = fmaf(s0, w01, s1) + bl[k * 3 + 1];
        z2 = fmaf(s0, w02, fmaf(s1, w12, s2)) + bl[k * 3 + 2];

        // log|EPS + raw diag| — exactly as the TF source
        ld += __logf(fabsf(FLOW_EPS + w00))
            + __logf(fabsf(FLOW_EPS + w11))
            + __logf(fabsf(FLOW_EPS + w22));
    }
}

// Persistent, single-buffer-per-wave, reg-staged pipeline. 4 waves/block,
// 51 KiB LDS -> 3 blocks/CU -> 12 waves/CU (same occupancy as the best
// one-shot variant) AND cross-chunk overlap: while chunk k computes from
// registers, chunk k+1's 13 global_load_lds are in flight into the SAME
// LDS buffer (safe: k's data was moved LDS->reg and lgkmcnt(0) drained
// before re-issue; VMEM->LDS writes land hundreds of cycles later).
// Zero barriers anywhere.
__global__ __launch_bounds__(256) void graphflow_persistent(
    const float* __restrict__ z_in,
    const float* __restrict__ w_in,
    const float* __restrict__ b_in,
    float* __restrict__ out,
    int nchunks, int nwaves)
{
    // per wave: w 9x64 f4 (9 KiB), b 3x64 f4 (3 KiB), z 48 f4 (0.75 KiB)
    __shared__ float4 lds_w[4][576];
    __shared__ float4 lds_b[4][192];
    __shared__ float4 lds_z[4][48];

    const int wave = threadIdx.x >> 6;
    const int lane = threadIdx.x & 63;
    const int gwave = blockIdx.x * 4 + wave;

    if (gwave >= nchunks) return;  // no barriers -> early return safe
    const int myn = (nchunks - gwave + nwaves - 1) / nwaves;

    const float4* wv = reinterpret_cast<const float4*>(w_in);
    const float4* bv = reinterpret_cast<const float4*>(b_in);
    const float4* zv = reinterpret_cast<const float4*>(z_in);
    float4* ov = reinterpret_cast<float4*>(out);

    // Issue 13 global_load_lds for one chunk into this wave's buffer.
    auto issue = [&](long long chunk) {
        const float4* wg = wv + chunk * 576;  // 64 el * 9 f4
        const float4* bg = bv + chunk * 192;  // 64 el * 3 f4
        const float4* zg = zv + chunk * 48;   // 64 el * 0.75 f4
#pragma unroll
        for (int j = 0; j < 9; ++j) {
            const int q = j * 64 + lane;
            __builtin_amdgcn_global_load_lds(
                (GLOBAL_AS)(wg + SWZ(q)),
                (LDS_AS)(&lds_w[wave][j * 64]), 16, 0, 0);
        }
#pragma unroll
        for (int j = 0; j < 3; ++j) {
            const int q = j * 64 + lane;
            __builtin_amdgcn_global_load_lds(
                (GLOBAL_AS)(bg + SWZ(q)),
                (LDS_AS)(&lds_b[wave][j * 64]), 16, 0, 0);
        }
        if (lane < 48) {  // 768 B of z; 1 VMEM instr (partial exec)
            __builtin_amdgcn_global_load_lds(
                (GLOBAL_AS)(zg + lane),
                (LDS_AS)(&lds_z[wave][0]), 16, 0, 0);
        }
    };

    issue(gwave);  // prologue

    for (int k = 0; k < myn; ++k) {
        const long long chunk = (long long)gwave + (long long)k * nwaves;

        // vmcnt ledger at loop top (oldest first):
        //  k==0:          [13 ld c0]                          -> wait 0
        //  k>=1:          [(st c(k-2))? drained][13 ld ck][st c(k-1)]
        //                 queue = 13 loads + 1 newest store   -> wait 1
        if (k == 0) { WAITVM(0); } else { WAITVM(1); }
        __builtin_amdgcn_sched_barrier(0);

        // LDS -> registers (whole chunk: 12 f4 + 3 f32 per thread)
        float wl[36];
#pragma unroll
        for (int s = 0; s < 9; ++s) {
            const int f = 9 * lane + s;
            const float4 t = lds_w[wave][SWZ(f)];
            wl[4 * s + 0] = t.x; wl[4 * s + 1] = t.y;
            wl[4 * s + 2] = t.z; wl[4 * s + 3] = t.w;
        }
        float bl[12];
#pragma unroll
        for (int s = 0; s < 3; ++s) {
            const int f = 3 * lane + s;
            const float4 t = lds_b[wave][SWZ(f)];
            bl[4 * s + 0] = t.x; bl[4 * s + 1] = t.y;
            bl[4 * s + 2] = t.z; bl[4 * s + 3] = t.w;
        }
        const float* zf = reinterpret_cast<const float*>(&lds_z[wave][0]);
        float z0 = zf[3 * lane + 0];  // bank = 3*lane % 32: <=2-way (free)
        float z1 = zf[3 * lane + 1];
        float z2 = zf[3 * lane + 2];

        // Drain ds_reads, then (and only then) re-issue into the same buffer.
        WAITLGKM0();
        __builtin_amdgcn_sched_barrier(0);
        if (k + 1 < myn) issue(chunk + nwaves);

        float ld = 0.0f;
        flow_compute(wl, bl, z0, z1, z2, ld);

        ov[chunk * 64 + lane] = make_float4(z0, z1, z2, ld);
    }
}

// Tail: elements beyond the last full 64-chunk (not hit for B = 2^21).
__global__ __launch_bounds__(256) void graphflow_tail_kernel(
    const float* __restrict__ z_in,
    const float* __restrict__ w_in,
    const float* __restrict__ b_in,
    float* __restrict__ out,
    int start, int B)
{
    const int i = start + blockIdx.x * blockDim.x + threadIdx.x;
    if (i >= B) return;

    const float4* wv = reinterpret_cast<const float4*>(w_in) + (size_t)i * 9;
    const float4* bv = reinterpret_cast<const float4*>(b_in) + (size_t)i * 3;

    float wl[36];
#pragma unroll
    for (int j = 0; j < 9; ++j) {
        float4 t = wv[j];
        wl[j * 4 + 0] = t.x; wl[j * 4 + 1] = t.y;
        wl[j * 4 + 2] = t.z; wl[j * 4 + 3] = t.w;
    }
    float bl[12];
#pragma unroll
    for (int j = 0; j < 3; ++j) {
        float4 t = bv[j];
        bl[j * 4 + 0] = t.x; bl[j * 4 + 1] = t.y;
        bl[j * 4 + 2] = t.z; bl[j * 4 + 3] = t.w;
    }

    float z0 = z_in[(size_t)i * 3 + 0];
    float z1 = z_in[(size_t)i * 3 + 1];
    float z2 = z_in[(size_t)i * 3 + 2];
    float ld = 0.0f;
    flow_compute(wl, bl, z0, z1, z2, ld);
    reinterpret_cast<float4*>(out)[i] = make_float4(z0, z1, z2, ld);
}

extern "C" void kernel_launch(void* const* d_in, const int* in_sizes, int n_in,
                              void* d_out, int out_size, void* d_ws, size_t ws_size,
                              hipStream_t stream) {
    const float* z = (const float*)d_in[0];
    const float* w = (const float*)d_in[1];
    const float* b = (const float*)d_in[2];
    float* out = (float*)d_out;

    const int B = in_sizes[0] / 3;   // z is [B,3]
    const int nchunks = B / 64;      // full 64-element chunks

    if (nchunks > 0) {
        const int grid = 768;        // 3 blocks/CU x 256 CU (51 KiB LDS/block)
        const int nwaves = grid * 4; // 12 waves/CU
        graphflow_persistent<<<grid, 256, 0, stream>>>(z, w, b, out,
                                                       nchunks, nwaves);
    }
    const int rem_start = nchunks * 64;
    const int rem = B - rem_start;
    if (rem > 0) {
        graphflow_tail_kernel<<<(rem + 255) / 256, 256, 0, stream>>>(
            z, w, b, out, rem_start, B);
    }
}

// Round 6
// 89.361 us; speedup vs baseline: 1.0396x; 1.0396x over previous
//
#include <hip/hip_runtime.h>

#define FLOW_EPS 0.1f

// XOR involution used on both the global-source index (pre-swizzle) and the
// LDS read index (rule #21: both-sides-or-neither with global_load_lds).
// Bijective on any multiple-of-8 range (only touches bits 0-2, keyed off bits
// 4-6). Makes the per-thread stride-9 float4 reads bank-balanced while keeping
// global_load_lds sources a within-1KiB permutation (fully coalesced).
#define SWZ(f) ((f) ^ (((f) >> 4) & 7))

__device__ __forceinline__ void flow_compute(const float* wl, const float* bl,
                                             float& z0, float& z1, float& z2,
                                             float& ld)
{
#pragma unroll
    for (int k = 0; k < 4; ++k) {
        const int o = k * 9;
        const float w00 = wl[o + 0], w01 = wl[o + 1], w02 = wl[o + 2];
        const float w10 = wl[o + 3], w11 = wl[o + 4], w12 = wl[o + 5];
        const float w20 = wl[o + 6], w21 = wl[o + 7], w22 = wl[o + 8];

        const float d0 = fabsf(w00) + FLOW_EPS;
        const float d1 = fabsf(w11) + FLOW_EPS;
        const float d2 = fabsf(w22) + FLOW_EPS;

        // t = z @ L (unit lower-tri)
        const float t0 = fmaf(z2, w20, fmaf(z1, w10, z0));
        const float t1 = fmaf(z2, w21, z1);
        const float t2 = z2;
        // s = t * d
        const float s0 = t0 * d0;
        const float s1 = t1 * d1;
        const float s2 = t2 * d2;
        // z = s @ U + b (unit upper-tri)
        z0 = s0 + bl[k * 3 + 0];
        z1 = fmaf(s0, w01, s1) + bl[k * 3 + 1];
        z2 = fmaf(s0, w02, fmaf(s1, w12, s2)) + bl[k * 3 + 2];

        // log|EPS + raw diag| — exactly as the TF source
        ld += __logf(fabsf(FLOW_EPS + w00))
            + __logf(fabsf(FLOW_EPS + w11))
            + __logf(fabsf(FLOW_EPS + w22));
    }
}

// Main kernel: full 256-thread blocks only (grid = B/256).
// Per-wave LDS staging: each wave stages its own 64 elements.
__global__ __launch_bounds__(256) void graphflow_kernel(
    const float* __restrict__ z_in,
    const float* __restrict__ w_in,
    const float* __restrict__ b_in,
    float* __restrict__ out)
{
    __shared__ float4 lds_w[4][576];  // 9 float4 x 64 el per wave
    __shared__ float4 lds_b[4][192];  // 3 float4 x 64 el per wave

    const int tid  = threadIdx.x;
    const int wave = tid >> 6;
    const int lane = tid & 63;

    const long long blockBase = (long long)blockIdx.x * 256;
    const long long waveBase  = blockBase + (long long)wave * 64;

    const float4* wg = reinterpret_cast<const float4*>(w_in) + waveBase * 9;
    const float4* bg = reinterpret_cast<const float4*>(b_in) + waveBase * 3;

    // stage w: 9 wave-wide 1KiB DMA ops, swizzled source -> linear LDS dest
#pragma unroll
    for (int j = 0; j < 9; ++j) {
        const int q = j * 64 + lane;
        __builtin_amdgcn_global_load_lds(
            (const __attribute__((address_space(1))) void*)(wg + SWZ(q)),
            (__attribute__((address_space(3))) void*)(&lds_w[wave][j * 64]),
            16, 0, 0);
    }
    // stage b: 3 wave-wide DMA ops
#pragma unroll
    for (int j = 0; j < 3; ++j) {
        const int q = j * 64 + lane;
        __builtin_amdgcn_global_load_lds(
            (const __attribute__((address_space(1))) void*)(bg + SWZ(q)),
            (__attribute__((address_space(3))) void*)(&lds_b[wave][j * 64]),
            16, 0, 0);
    }

    // z: direct coalesced scalar loads (12 B/el, dense)
    const long long i = blockBase + tid;
    float z0 = z_in[i * 3 + 0];
    float z1 = z_in[i * 3 + 1];
    float z2 = z_in[i * 3 + 2];

    __syncthreads();  // drains vmcnt(0): LDS populated

    // gather this thread's w (9 float4) and b (3 float4), swizzled reads
    float wl[36];
#pragma unroll
    for (int s = 0; s < 9; ++s) {
        const int f = 9 * lane + s;
        const float4 t = lds_w[wave][SWZ(f)];
        wl[4 * s + 0] = t.x; wl[4 * s + 1] = t.y;
        wl[4 * s + 2] = t.z; wl[4 * s + 3] = t.w;
    }
    float bl[12];
#pragma unroll
    for (int s = 0; s < 3; ++s) {
        const int f = 3 * lane + s;
        const float4 t = lds_b[wave][SWZ(f)];
        bl[4 * s + 0] = t.x; bl[4 * s + 1] = t.y;
        bl[4 * s + 2] = t.z; bl[4 * s + 3] = t.w;
    }

    float ld = 0.0f;
    flow_compute(wl, bl, z0, z1, z2, ld);

    reinterpret_cast<float4*>(out)[i] = make_float4(z0, z1, z2, ld);
}

// Tail kernel (only if B % 256 != 0): direct-load path, one thread per element.
__global__ __launch_bounds__(256) void graphflow_tail_kernel(
    const float* __restrict__ z_in,
    const float* __restrict__ w_in,
    const float* __restrict__ b_in,
    float* __restrict__ out,
    int start, int B)
{
    const int i = start + blockIdx.x * blockDim.x + threadIdx.x;
    if (i >= B) return;

    const float4* wv = reinterpret_cast<const float4*>(w_in) + (size_t)i * 9;
    const float4* bv = reinterpret_cast<const float4*>(b_in) + (size_t)i * 3;

    float wl[36];
#pragma unroll
    for (int j = 0; j < 9; ++j) {
        float4 t = wv[j];
        wl[j * 4 + 0] = t.x; wl[j * 4 + 1] = t.y;
        wl[j * 4 + 2] = t.z; wl[j * 4 + 3] = t.w;
    }
    float bl[12];
#pragma unroll
    for (int j = 0; j < 3; ++j) {
        float4 t = bv[j];
        bl[j * 4 + 0] = t.x; bl[j * 4 + 1] = t.y;
        bl[j * 4 + 2] = t.z; bl[j * 4 + 3] = t.w;
    }

    float z0 = z_in[(size_t)i * 3 + 0];
    float z1 = z_in[(size_t)i * 3 + 1];
    float z2 = z_in[(size_t)i * 3 + 2];
    float ld = 0.0f;
    flow_compute(wl, bl, z0, z1, z2, ld);
    reinterpret_cast<float4*>(out)[i] = make_float4(z0, z1, z2, ld);
}

extern "C" void kernel_launch(void* const* d_in, const int* in_sizes, int n_in,
                              void* d_out, int out_size, void* d_ws, size_t ws_size,
                              hipStream_t stream) {
    const float* z = (const float*)d_in[0];
    const float* w = (const float*)d_in[1];
    const float* b = (const float*)d_in[2];
    float* out = (float*)d_out;

    const int B = in_sizes[0] / 3;      // z is [B,3]
    const int full_blocks = B / 256;    // B = 2,097,152 -> 8192 exact

    if (full_blocks > 0) {
        graphflow_kernel<<<full_blocks, 256, 0, stream>>>(z, w, b, out);
    }
    const int rem_start = full_blocks * 256;
    const int rem = B - rem_start;
    if (rem > 0) {
        graphflow_tail_kernel<<<(rem + 255) / 256, 256, 0, stream>>>(
            z, w, b, out, rem_start, B);
    }
}